// Round 1
// baseline (859.432 us; speedup 1.0000x reference)
//
#include <hip/hip_runtime.h>

#define NQ 14
#define NL 6
#define DIM (1 << NQ)   // 16384 amplitudes
#define TPB 256

// One block per sample. State lives entirely in (dynamic) LDS: 16384 float2 = 128 KiB.
// Gate matrices (98 x 2x2 complex) precomputed per block into static LDS.
// FC layer fused into the probability reduction.

__global__ __launch_bounds__(TPB, 1)
void qc_kernel(const float* __restrict__ x,
               const float* __restrict__ wts,
               const float* __restrict__ fcw,
               const float* __restrict__ fcb,
               float* __restrict__ out)
{
    extern __shared__ float2 st[];          // DIM float2 = 128 KiB
    __shared__ float2 U[NL * NQ + NQ][4];   // Rot gates [0..83], RX gates [84..97]
    __shared__ float wsum[TPB / 64];

    const int b   = blockIdx.x;
    const int tid = threadIdx.x;

    // ---- precompute gate matrices ----
    if (tid < NQ) {
        // RX(x[b][w]) = [[c, -i s], [-i s, c]], c=cos(x/2), s=sin(x/2)
        float th = 0.5f * x[b * NQ + tid];
        float c = cosf(th), s = sinf(th);
        float2* u = U[NL * NQ + tid];
        u[0] = make_float2(c, 0.f);
        u[1] = make_float2(0.f, -s);
        u[2] = make_float2(0.f, -s);
        u[3] = make_float2(c, 0.f);
    }
    if (tid >= 64 && tid < 64 + NL * NQ) {
        // Rot(phi,theta,omega) = RZ(omega) RY(theta) RZ(phi)
        int g = tid - 64;
        int l = g / NQ, q = g % NQ;
        float phi = wts[(l * NQ + q) * 3 + 0];
        float th  = wts[(l * NQ + q) * 3 + 1];
        float om  = wts[(l * NQ + q) * 3 + 2];
        float c = cosf(0.5f * th), s = sinf(0.5f * th);
        float a = 0.5f * (phi + om), d = 0.5f * (phi - om);
        float ca = cosf(a), sa = sinf(a);
        float cd = cosf(d), sd = sinf(d);
        float2* u = U[g];
        u[0] = make_float2( ca * c, -sa * c);   // e^{-i a} c
        u[1] = make_float2(-cd * s, -sd * s);   // -e^{+i d} s
        u[2] = make_float2( cd * s, -sd * s);   // e^{-i d} s
        u[3] = make_float2( ca * c,  sa * c);   // e^{+i a} c
    }

    // ---- init |0...0> ----
    for (int i = tid; i < DIM; i += TPB)
        st[i] = (i == 0) ? make_float2(1.f, 0.f) : make_float2(0.f, 0.f);
    __syncthreads();

    // ---- single-qubit gate: wire w pairs amplitudes differing in bit (13-w) ----
    auto apply1 = [&](int wire, const float2* __restrict__ um) {
        const int bp     = NQ - 1 - wire;
        const int stride = 1 << bp;
        const float2 u0 = um[0], u1 = um[1], u2 = um[2], u3 = um[3];
        for (int p = tid; p < DIM / 2; p += TPB) {
            int i0 = ((p >> bp) << (bp + 1)) | (p & (stride - 1));
            int i1 = i0 | stride;
            float2 a = st[i0], c = st[i1];
            float2 r0, r1;
            r0.x = u0.x * a.x - u0.y * a.y + u1.x * c.x - u1.y * c.y;
            r0.y = u0.x * a.y + u0.y * a.x + u1.x * c.y + u1.y * c.x;
            r1.x = u2.x * a.x - u2.y * a.y + u3.x * c.x - u3.y * c.y;
            r1.y = u2.x * a.y + u2.y * a.x + u3.x * c.y + u3.y * c.x;
            st[i0] = r0;
            st[i1] = r1;
        }
        __syncthreads();
    };

    // ---- CNOT(ctrl,tgt): swap amplitudes where ctrl=1, over tgt bit ----
    auto cnot = [&](int ctrl, int tgt) {
        const int bc = NQ - 1 - ctrl, bt = NQ - 1 - tgt;
        const int b1 = bc < bt ? bc : bt;
        const int b2 = bc < bt ? bt : bc;
        for (int p = tid; p < DIM / 4; p += TPB) {
            int low  = p & ((1 << b1) - 1);
            int mid  = (p >> b1) & ((1 << (b2 - b1 - 1)) - 1);
            int high = p >> (b2 - 1);
            int i = (high << (b2 + 1)) | (mid << (b1 + 1)) | low | (1 << bc);
            int j = i | (1 << bt);
            float2 a = st[i], c = st[j];
            st[i] = c;
            st[j] = a;
        }
        __syncthreads();
    };

    // ---- circuit ----
    for (int q = 0; q < NQ; ++q)
        apply1(q, U[NL * NQ + q]);                 // AngleEmbedding RX

    for (int l = 0; l < NL; ++l) {
        for (int q = 0; q < NQ; ++q)
            apply1(q, U[l * NQ + q]);              // Rot layer
        int r = (l % (NQ - 1)) + 1;
        for (int q = 0; q < NQ; ++q)
            cnot(q, (q + r) % NQ);                 // entangler ring
    }

    // ---- fused expectation + FC:  out[b] = sum_i |psi_i|^2 * g(i) + fc_b ----
    float fw[NQ];
#pragma unroll
    for (int q = 0; q < NQ; ++q) fw[q] = fcw[q];

    float acc = 0.f;
    for (int i = tid; i < DIM; i += TPB) {
        float2 a = st[i];
        float p = a.x * a.x + a.y * a.y;
        float g = 0.f;
#pragma unroll
        for (int q = 0; q < NQ; ++q)
            g += ((i >> (NQ - 1 - q)) & 1) ? -fw[q] : fw[q];
        acc += p * g;
    }
#pragma unroll
    for (int off = 32; off > 0; off >>= 1)
        acc += __shfl_down(acc, off, 64);
    if ((tid & 63) == 0) wsum[tid >> 6] = acc;
    __syncthreads();
    if (tid == 0) {
        float t = 0.f;
#pragma unroll
        for (int wv = 0; wv < TPB / 64; ++wv) t += wsum[wv];
        out[b] = t + fcb[0];
    }
}

extern "C" void kernel_launch(void* const* d_in, const int* in_sizes, int n_in,
                              void* d_out, int out_size, void* d_ws, size_t ws_size,
                              hipStream_t stream)
{
    const float* x   = (const float*)d_in[0];   // (512, 14)
    const float* wts = (const float*)d_in[1];   // (6, 14, 3)
    const float* fcw = (const float*)d_in[2];   // (1, 14)
    const float* fcb = (const float*)d_in[3];   // (1,)
    float* out = (float*)d_out;                 // (512,)

    const int batch = in_sizes[0] / NQ;         // 512
    const size_t lds_bytes = (size_t)DIM * sizeof(float2);  // 131072

    static bool attr_set = false;
    if (!attr_set) {
        (void)hipFuncSetAttribute((const void*)qc_kernel,
                                  hipFuncAttributeMaxDynamicSharedMemorySize,
                                  (int)lds_bytes);
        attr_set = true;
    }

    qc_kernel<<<batch, TPB, lds_bytes, stream>>>(x, wts, fcw, fcb, out);
}